// Round 8
// baseline (32.818 us; speedup 1.0000x reference)
//
#include <hip/hip_runtime.h>
#include <math.h>

// Fused DETR HungarianMatcher cost matrix:
//   C[nq, t] = 5*L1(pred_cxcywh, tgt_cxcywh) + 2*focal_cls(prob[nq, lab[t]])
//              - 2*GIoU(pred_xyxy, tgt_xyxy)
// NQ = 14400, T = 1600. Output f32 [NQ, T].
//
// Round-8: break the write/compute serialization.
//   Model from R3/R5/R7: dur = 24.3us + VALU_us (slope 1.0) -> stores
//   back-pressure compute. Fixes:
//   - NONTEMPORAL float4 stores (global_store_dwordx4 nt): stream 92MB past
//     L2, 1KB/wave-store (same pattern as the 6.8TB/s harness fill).
//   - quad (4 t) per thread, NTHR=128 -> 400/128 = 3.125 iters (small tail).
//   - all |.| folded into free VOP3 abs modifiers; pk math elsewhere.
//   Kept: containment-safe overlap identity, one rcp/output, folded weights,
//   clamped-index register prefetch, 32-bit store indexing.

#define NCLS  80
#define QTILE 4
#define NTHR  128

typedef float v2f __attribute__((ext_vector_type(2)));
typedef float v4f __attribute__((ext_vector_type(4)));

static __device__ __forceinline__ v2f v2(float a, float b) { v2f r; r.x = a; r.y = b; return r; }

// cost for one query vs a pair of targets (packed)
static __device__ __forceinline__ v2f cost_pair(
    float qcx, float qcy, float qw, float qh, float qwh, float qhh, float qa,
    v2f bcx, v2f bcy, v2f bw, v2f bh, v2f bwh, v2f bhh, v2f ba, v2f cls)
{
    v2f dcx = qcx - bcx, dcy = qcy - bcy;     // pk
    v2f dw  = qw  - bw,  dh  = qh  - bh;      // pk
    // L1: scalar adds, |.| free as VOP3 input modifiers
    float l1x = (fabsf(dcx.x) + fabsf(dcy.x)) + (fabsf(dw.x) + fabsf(dh.x));
    float l1y = (fabsf(dcx.y) + fabsf(dcy.y)) + (fabsf(dw.y) + fabsf(dh.y));

    v2f hw  = qwh + bwh,  hh  = qhh + bhh;    // pk
    v2f dwh = qwh - bwh,  dhh = qhh - bhh;    // pk
    // signed 1-D overlap: iwd = hw - max(|dcx|, |dwh|)  (containment-safe)
    v2f ew = v2(fmaxf(fabsf(dcx.x), fabsf(dwh.x)),
                fmaxf(fabsf(dcx.y), fabsf(dwh.y)));     // scalar max, abs free
    v2f eh = v2(fmaxf(fabsf(dcy.x), fabsf(dhh.x)),
                fmaxf(fabsf(dcy.y), fabsf(dhh.y)));
    v2f iwd = hw - ew, ihd = hh - eh;                   // pk
    v2f iw = v2(fmaxf(iwd.x, 0.f), fmaxf(iwd.y, 0.f));
    v2f ih = v2(fmaxf(ihd.x, 0.f), fmaxf(ihd.y, 0.f));
    v2f inter = iw * ih;                                // pk
    v2f uni = (qa + ba) - inter;                        // pk x2
    v2f cw = 2.0f * hw - iwd, ch = 2.0f * hh - ihd;     // pk fma
    v2f ca = cw * ch;                                   // pk

    // cost = 5*l1 + (2*cls+2) - 2*(inter*ca + uni^2)/(uni*ca)
    v2f base = 5.0f * v2(l1x, l1y) + cls;               // pk fma
    v2f den  = uni * ca;                                // pk
    v2f r    = v2(__builtin_amdgcn_rcpf(den.x),
                  __builtin_amdgcn_rcpf(den.y));        // trans, ~1 ulp
    v2f num  = uni * uni + inter * ca;                  // pk x2
    return -2.0f * (num * r) + base;                    // pk x2
}

static __device__ __forceinline__ float qsel(float4 c, int q) {
    return (q == 0) ? c.x : (q == 1) ? c.y : (q == 2) ? c.z : c.w;
}

__global__ __launch_bounds__(NTHR)
void matcher_cost_kernel(const float* __restrict__ logits,   // [NQ, 80]
                         const float* __restrict__ pboxes,   // [NQ, 4] cxcywh
                         const float* __restrict__ tboxes,   // [T, 4] xyxy
                         const int*   __restrict__ tlabels,  // [T]
                         float* __restrict__ out,            // [NQ, T]
                         int NQ, int T)
{
    __shared__ float ccT[NCLS][QTILE];   // [label][q] : 2*cls + 2 (weights folded)

    const int tid = threadIdx.x;
    const int q0  = blockIdx.x * QTILE;   // NQ % 4 == 0

    // --- focal table: coalesced read of the block's contiguous 320 logits ---
    for (int i = tid; i < QTILE * NCLS; i += NTHR) {
        int q = i / NCLS, lab = i - q * NCLS;
        float x = logits[(size_t)q0 * NCLS + i];
        float p = 1.0f / (1.0f + __expf(-x));
        float pos = 0.25f * (1.0f - p) * (1.0f - p) * (-__logf(p + 1e-8f));
        float neg = 0.75f * p * p * (-__logf(1.0f - p + 1e-8f));
        ccT[lab][q] = 2.0f * (pos - neg) + 2.0f;
    }

    // --- per-query state (wave-uniform): 7 scalars per q ---
    float qcx[QTILE], qcy[QTILE], qw[QTILE], qh[QTILE];
    float qwh[QTILE], qhh[QTILE], qa[QTILE];
#pragma unroll
    for (int q = 0; q < QTILE; ++q) {
        float4 pb = reinterpret_cast<const float4*>(pboxes)[q0 + q];
        qcx[q] = pb.x; qcy[q] = pb.y; qw[q] = pb.z; qh[q] = pb.w;
        qwh[q] = 0.5f * pb.z; qhh[q] = 0.5f * pb.w;
        qa[q]  = pb.z * pb.w;   // == (x2-x1)*(y2-y1) for w,h>0
    }
    __syncthreads();

    const float4* tb4 = reinterpret_cast<const float4*>(tboxes);
    const int4*   lb4 = reinterpret_cast<const int4*>(tlabels);
    const float4* ccv = reinterpret_cast<const float4*>(ccT);

    const int nquad = T >> 2;                        // 400
    v4f* obase = reinterpret_cast<v4f*>(out) + (size_t)q0 * nquad;

    int quad = tid;                                  // tid < 128 <= nquad: valid
    float4 b0 = tb4[4 * quad],     b1 = tb4[4 * quad + 1];
    float4 b2 = tb4[4 * quad + 2], b3 = tb4[4 * quad + 3];
    int4 L = lb4[quad];

    for (;;) {
        const int  nxt  = quad + NTHR;
        const bool more = nxt < nquad;
        const int  nc   = more ? nxt : quad;         // clamped: branch-free loads
        float4 nb0 = tb4[4 * nc],     nb1 = tb4[4 * nc + 1];
        float4 nb2 = tb4[4 * nc + 2], nb3 = tb4[4 * nc + 3];
        int4   nL  = lb4[nc];

        // class gather: one b128 per target serves all 4 queries
        float4 c0 = ccv[L.x], c1 = ccv[L.y], c2 = ccv[L.z], c3 = ccv[L.w];

        // pair A = (t0,t1), pair B = (t2,t3); element j of v2f = target j of pair
        v2f aX1 = v2(b0.x, b1.x), aY1 = v2(b0.y, b1.y);
        v2f aX2 = v2(b0.z, b1.z), aY2 = v2(b0.w, b1.w);
        v2f bX1 = v2(b2.x, b3.x), bY1 = v2(b2.y, b3.y);
        v2f bX2 = v2(b2.z, b3.z), bY2 = v2(b2.w, b3.w);

        v2f aw  = aX2 - aX1, ah = aY2 - aY1;
        v2f acx = 0.5f * (aX1 + aX2), acy = 0.5f * (aY1 + aY2);
        v2f aa  = aw * ah, awh = 0.5f * aw, ahh = 0.5f * ah;
        v2f bw  = bX2 - bX1, bh = bY2 - bY1;
        v2f bcx = 0.5f * (bX1 + bX2), bcy = 0.5f * (bY1 + bY2);
        v2f ba  = bw * bh, bwh = 0.5f * bw, bhh = 0.5f * bh;

#pragma unroll
        for (int q = 0; q < QTILE; ++q) {
            v2f rA = cost_pair(qcx[q], qcy[q], qw[q], qh[q], qwh[q], qhh[q], qa[q],
                               acx, acy, aw, ah, awh, ahh, aa,
                               v2(qsel(c0, q), qsel(c1, q)));
            v2f rB = cost_pair(qcx[q], qcy[q], qw[q], qh[q], qwh[q], qhh[q], qa[q],
                               bcx, bcy, bw, bh, bwh, bhh, ba,
                               v2(qsel(c2, q), qsel(c3, q)));
            v4f res; res.x = rA.x; res.y = rA.y; res.z = rB.x; res.w = rB.y;
            // streaming store: bypass L2 write-allocate (nt)
            __builtin_nontemporal_store(res, obase + q * nquad + quad);
        }

        if (!more) break;
        quad = nxt; b0 = nb0; b1 = nb1; b2 = nb2; b3 = nb3; L = nL;
    }
}

extern "C" void kernel_launch(void* const* d_in, const int* in_sizes, int n_in,
                              void* d_out, int out_size, void* d_ws, size_t ws_size,
                              hipStream_t stream) {
    const float* logits  = (const float*)d_in[0];  // [16,900,80]
    const float* pboxes  = (const float*)d_in[1];  // [16,900,4]
    const float* tboxes  = (const float*)d_in[2];  // [1600,4]
    const int*   tlabels = (const int*)d_in[3];    // [1600]
    float* out = (float*)d_out;

    const int NQ = in_sizes[1] / 4;   // 14400
    const int T  = in_sizes[2] / 4;   // 1600

    const int nblocks = (NQ + QTILE - 1) / QTILE;  // 3600
    matcher_cost_kernel<<<nblocks, NTHR, 0, stream>>>(logits, pboxes, tboxes,
                                                      tlabels, out, NQ, T);
}

// Round 9
// 30.703 us; speedup vs baseline: 1.0689x; 1.0689x over previous
//
#include <hip/hip_runtime.h>
#include <math.h>

// Fused DETR HungarianMatcher cost matrix:
//   C[nq, t] = 5*L1(pred_cxcywh, tgt_cxcywh) + 2*focal_cls(prob[nq, lab[t]])
//              - 2*GIoU(pred_xyxy, tgt_xyxy)
// NQ = 14400, T = 1600. Output f32 [NQ, T].
//
// Round-9 = Round-7 (best: 31.2us) + final VALU trim; R8's nt/NTHR=128
// reverted (regressed to 32.8).
//   - half-extent reuse: dwh = qwh-bwh serves BOTH the overlap test and the
//     L1 w/h term: l1 = (|dcx|+|dcy|) + 2*(|dwh|+|dhh|)  (one fma; deletes
//     the dw,dh pk-subs).
//   - shared block: ba = 4*bwh*bhh (bw,bh no longer materialized).
//   - model (R3/R5/R7/R8): dur = 24.3us + VALU_us, slope 1.0. Base =
//     13.7us HBM writes + ~9us graph overhead. This cut is the last ~1us of
//     trimmable VALU; if flat -> declare roofline.

#define NCLS  80
#define QTILE 4
#define NTHR  256

typedef float v2f __attribute__((ext_vector_type(2)));

static __device__ __forceinline__ v2f v2(float a, float b) { v2f r; r.x = a; r.y = b; return r; }

__global__ __launch_bounds__(NTHR)
void matcher_cost_kernel(const float* __restrict__ logits,   // [NQ, 80]
                         const float* __restrict__ pboxes,   // [NQ, 4] cxcywh
                         const float* __restrict__ tboxes,   // [T, 4] xyxy
                         const int*   __restrict__ tlabels,  // [T]
                         float* __restrict__ out,            // [NQ, T]
                         int NQ, int T)
{
    __shared__ float ccT[NCLS][QTILE];   // [label][q] : 2*cls + 2 (weights folded)

    const int tid = threadIdx.x;
    const int q0  = blockIdx.x * QTILE;   // NQ % 4 == 0

    // --- focal table: coalesced read of the block's contiguous 320 logits ---
    for (int i = tid; i < QTILE * NCLS; i += NTHR) {
        int q = i / NCLS, lab = i - q * NCLS;
        float x = logits[(size_t)q0 * NCLS + i];
        float p = 1.0f / (1.0f + __expf(-x));
        float pos = 0.25f * (1.0f - p) * (1.0f - p) * (-__logf(p + 1e-8f));
        float neg = 0.75f * p * p * (-__logf(1.0f - p + 1e-8f));
        ccT[lab][q] = 2.0f * (pos - neg) + 2.0f;
    }

    // --- per-query state (wave-uniform): cx, cy, half-w, half-h, area ---
    float qcx[QTILE], qcy[QTILE], qwh[QTILE], qhh[QTILE], qa[QTILE];
#pragma unroll
    for (int q = 0; q < QTILE; ++q) {
        float4 pb = reinterpret_cast<const float4*>(pboxes)[q0 + q];
        qcx[q] = pb.x; qcy[q] = pb.y;
        qwh[q] = 0.5f * pb.z; qhh[q] = 0.5f * pb.w;
        qa[q]  = pb.z * pb.w;   // == (x2-x1)*(y2-y1) for w,h>0
    }
    __syncthreads();

    const float4* tb4 = reinterpret_cast<const float4*>(tboxes);
    const int2*   lb2 = reinterpret_cast<const int2*>(tlabels);
    const float4* ccv = reinterpret_cast<const float4*>(ccT);

    const int npair = T >> 1;                        // 800
    float2* obase = reinterpret_cast<float2*>(out) + (size_t)q0 * npair;

    int pair = tid;                                  // tid < 256 <= npair: valid
    float4 b0 = tb4[pair * 2], b1 = tb4[pair * 2 + 1];
    int2 L = lb2[pair];

    for (;;) {
        const int  nxt  = pair + NTHR;
        const bool more = nxt < npair;
        const int  nc   = more ? nxt : pair;         // clamped: branch-free loads
        float4 nb0 = tb4[nc * 2], nb1 = tb4[nc * 2 + 1];
        int2   nL  = lb2[nc];

        // class gather: one b128 per target serves all 4 queries
        float4 c0 = ccv[L.x], c1 = ccv[L.y];

        // shared per-target math (element j of v2f = target 2*pair+j)
        v2f bX1 = v2(b0.x, b1.x), bY1 = v2(b0.y, b1.y);
        v2f bX2 = v2(b0.z, b1.z), bY2 = v2(b0.w, b1.w);
        v2f bcx = 0.5f * (bX1 + bX2);                // pk add + pk mul
        v2f bcy = 0.5f * (bY1 + bY2);
        v2f bwh = 0.5f * (bX2 - bX1);                // half extents
        v2f bhh = 0.5f * (bY2 - bY1);
        v2f ba  = 4.0f * (bwh * bhh);                // pk mul + pk mul

#pragma unroll
        for (int q = 0; q < QTILE; ++q) {
            v2f dcx = qcx[q] - bcx, dcy = qcy[q] - bcy;   // pk
            v2f dwh = qwh[q] - bwh, dhh = qhh[q] - bhh;   // pk (shared: L1 + overlap)
            v2f hw  = qwh[q] + bwh, hh  = qhh[q] + bhh;   // pk

            // L1 = |dcx|+|dcy| + 2*(|dwh|+|dhh|)   (abs free as VOP3 mods)
            float sxy_x = fabsf(dcx.x) + fabsf(dcy.x);
            float sxy_y = fabsf(dcx.y) + fabsf(dcy.y);
            float swh_x = fabsf(dwh.x) + fabsf(dhh.x);
            float swh_y = fabsf(dwh.y) + fabsf(dhh.y);
            float l1x = fmaf(2.0f, swh_x, sxy_x);
            float l1y = fmaf(2.0f, swh_y, sxy_y);

            // signed 1-D overlap: iwd = hw - max(|dcx|, |dwh|)  (containment-safe)
            v2f ew = v2(fmaxf(fabsf(dcx.x), fabsf(dwh.x)),
                        fmaxf(fabsf(dcx.y), fabsf(dwh.y)));
            v2f eh = v2(fmaxf(fabsf(dcy.x), fabsf(dhh.x)),
                        fmaxf(fabsf(dcy.y), fabsf(dhh.y)));
            v2f iwd = hw - ew, ihd = hh - eh;              // pk
            v2f iw = v2(fmaxf(iwd.x, 0.f), fmaxf(iwd.y, 0.f));
            v2f ih = v2(fmaxf(ihd.x, 0.f), fmaxf(ihd.y, 0.f));
            v2f inter = iw * ih;                           // pk
            v2f uni = (qa[q] + ba) - inter;                // pk x2
            v2f cw = 2.0f * hw - iwd;                      // pk fma
            v2f ch = 2.0f * hh - ihd;                      // pk fma
            v2f ca = cw * ch;                              // pk

            float clsa = (q == 0) ? c0.x : (q == 1) ? c0.y : (q == 2) ? c0.z : c0.w;
            float clsb = (q == 0) ? c1.x : (q == 1) ? c1.y : (q == 2) ? c1.z : c1.w;

            // cost = 5*l1 + (2*cls+2) - 2*(inter*ca + uni^2)/(uni*ca)
            v2f base = 5.0f * v2(l1x, l1y) + v2(clsa, clsb);   // pk fma
            v2f den  = uni * ca;                               // pk
            v2f r    = v2(__builtin_amdgcn_rcpf(den.x),
                          __builtin_amdgcn_rcpf(den.y));       // ~1 ulp
            v2f num  = uni * uni + inter * ca;                 // pk x2
            v2f res  = -2.0f * (num * r) + base;               // pk x2

            obase[q * npair + pair] = make_float2(res.x, res.y);
        }

        if (!more) break;
        pair = nxt; b0 = nb0; b1 = nb1; L = nL;
    }
}

extern "C" void kernel_launch(void* const* d_in, const int* in_sizes, int n_in,
                              void* d_out, int out_size, void* d_ws, size_t ws_size,
                              hipStream_t stream) {
    const float* logits  = (const float*)d_in[0];  // [16,900,80]
    const float* pboxes  = (const float*)d_in[1];  // [16,900,4]
    const float* tboxes  = (const float*)d_in[2];  // [1600,4]
    const int*   tlabels = (const int*)d_in[3];    // [1600]
    float* out = (float*)d_out;

    const int NQ = in_sizes[1] / 4;   // 14400
    const int T  = in_sizes[2] / 4;   // 1600

    const int nblocks = (NQ + QTILE - 1) / QTILE;  // 3600
    matcher_cost_kernel<<<nblocks, NTHR, 0, stream>>>(logits, pboxes, tboxes,
                                                      tlabels, out, NQ, T);
}

// Round 10
// 30.110 us; speedup vs baseline: 1.0899x; 1.0197x over previous
//
#include <hip/hip_runtime.h>
#include <math.h>

// Fused DETR HungarianMatcher cost matrix:
//   C[nq, t] = 5*L1(pred_cxcywh, tgt_cxcywh) + 2*focal_cls(prob[nq, lab[t]])
//              - 2*GIoU(pred_xyxy, tgt_xyxy)
// NQ = 14400, T = 1600. Output f32 [NQ, T].
//
// Round-10 = Round-9 (30.7us) with QTILE 4 -> 8:
//  - per-target shared math (13 pk/pair) amortized over 8 queries (1.6 ->
//    0.8 slots/output);
//  - 1800 blocks instead of 3600: half the block-startup events (table build
//    + cold loads; ~3.5 scheduling rounds of blocks, startup partly exposed).
//  - ~115 VGPR -> still 4 waves/SIMD; LDS 2.6KB; per-output LDS cost same.
// Model (R3/R5/R7/R8/R9): dur = 24.3us + VALU_us, slope 1.0. Base = 13.7us
// write drain + ~10us launch overhead (rocprof.md). This is the last in-model
// increment; if < 2% gain -> declare roofline.

#define NCLS  80
#define QTILE 8
#define NTHR  256

typedef float v2f __attribute__((ext_vector_type(2)));

static __device__ __forceinline__ v2f v2(float a, float b) { v2f r; r.x = a; r.y = b; return r; }
static __device__ __forceinline__ float qsel4(float4 c, int q) {
    return (q == 0) ? c.x : (q == 1) ? c.y : (q == 2) ? c.z : c.w;
}

__global__ __launch_bounds__(NTHR)
void matcher_cost_kernel(const float* __restrict__ logits,   // [NQ, 80]
                         const float* __restrict__ pboxes,   // [NQ, 4] cxcywh
                         const float* __restrict__ tboxes,   // [T, 4] xyxy
                         const int*   __restrict__ tlabels,  // [T]
                         float* __restrict__ out,            // [NQ, T]
                         int NQ, int T)
{
    __shared__ float ccT[NCLS][QTILE];   // [label][q] : 2*cls + 2 (weights folded)

    const int tid = threadIdx.x;
    const int q0  = blockIdx.x * QTILE;   // NQ % 8 == 0 (14400/8 = 1800)

    // --- focal table: coalesced read of the block's contiguous 640 logits ---
    for (int i = tid; i < QTILE * NCLS; i += NTHR) {
        int q = i / NCLS, lab = i - q * NCLS;
        float x = logits[(size_t)q0 * NCLS + i];
        float p = 1.0f / (1.0f + __expf(-x));
        float pos = 0.25f * (1.0f - p) * (1.0f - p) * (-__logf(p + 1e-8f));
        float neg = 0.75f * p * p * (-__logf(1.0f - p + 1e-8f));
        ccT[lab][q] = 2.0f * (pos - neg) + 2.0f;
    }

    // --- per-query state (wave-uniform): cx, cy, half-w, half-h, area ---
    float qcx[QTILE], qcy[QTILE], qwh[QTILE], qhh[QTILE], qa[QTILE];
#pragma unroll
    for (int q = 0; q < QTILE; ++q) {
        float4 pb = reinterpret_cast<const float4*>(pboxes)[q0 + q];
        qcx[q] = pb.x; qcy[q] = pb.y;
        qwh[q] = 0.5f * pb.z; qhh[q] = 0.5f * pb.w;
        qa[q]  = pb.z * pb.w;   // == (x2-x1)*(y2-y1) for w,h>0
    }
    __syncthreads();

    const float4* tb4 = reinterpret_cast<const float4*>(tboxes);
    const int2*   lb2 = reinterpret_cast<const int2*>(tlabels);
    const float4* ccv = reinterpret_cast<const float4*>(ccT);  // 2 float4 per label row

    const int npair = T >> 1;                        // 800
    float2* obase = reinterpret_cast<float2*>(out) + (size_t)q0 * npair;

    int pair = tid;                                  // tid < 256 <= npair: valid
    float4 b0 = tb4[pair * 2], b1 = tb4[pair * 2 + 1];
    int2 L = lb2[pair];

    for (;;) {
        const int  nxt  = pair + NTHR;
        const bool more = nxt < npair;
        const int  nc   = more ? nxt : pair;         // clamped: branch-free loads
        float4 nb0 = tb4[nc * 2], nb1 = tb4[nc * 2 + 1];
        int2   nL  = lb2[nc];

        // class gather: 2 x b128 per label -> 8 q values (per-output cost same)
        float4 c0lo = ccv[2 * L.x], c0hi = ccv[2 * L.x + 1];
        float4 c1lo = ccv[2 * L.y], c1hi = ccv[2 * L.y + 1];

        // shared per-target math (element j of v2f = target 2*pair+j)
        v2f bX1 = v2(b0.x, b1.x), bY1 = v2(b0.y, b1.y);
        v2f bX2 = v2(b0.z, b1.z), bY2 = v2(b0.w, b1.w);
        v2f bcx = 0.5f * (bX1 + bX2);
        v2f bcy = 0.5f * (bY1 + bY2);
        v2f bwh = 0.5f * (bX2 - bX1);                // half extents
        v2f bhh = 0.5f * (bY2 - bY1);
        v2f ba  = 4.0f * (bwh * bhh);

#pragma unroll
        for (int q = 0; q < QTILE; ++q) {
            v2f dcx = qcx[q] - bcx, dcy = qcy[q] - bcy;   // pk
            v2f dwh = qwh[q] - bwh, dhh = qhh[q] - bhh;   // pk (L1 + overlap shared)
            v2f hw  = qwh[q] + bwh, hh  = qhh[q] + bhh;   // pk

            // L1 = |dcx|+|dcy| + 2*(|dwh|+|dhh|)   (abs free as VOP3 mods)
            float sxy_x = fabsf(dcx.x) + fabsf(dcy.x);
            float sxy_y = fabsf(dcx.y) + fabsf(dcy.y);
            float swh_x = fabsf(dwh.x) + fabsf(dhh.x);
            float swh_y = fabsf(dwh.y) + fabsf(dhh.y);
            float l1x = fmaf(2.0f, swh_x, sxy_x);
            float l1y = fmaf(2.0f, swh_y, sxy_y);

            // signed 1-D overlap: iwd = hw - max(|dcx|, |dwh|)  (containment-safe)
            v2f ew = v2(fmaxf(fabsf(dcx.x), fabsf(dwh.x)),
                        fmaxf(fabsf(dcx.y), fabsf(dwh.y)));
            v2f eh = v2(fmaxf(fabsf(dcy.x), fabsf(dhh.x)),
                        fmaxf(fabsf(dcy.y), fabsf(dhh.y)));
            v2f iwd = hw - ew, ihd = hh - eh;              // pk
            v2f iw = v2(fmaxf(iwd.x, 0.f), fmaxf(iwd.y, 0.f));
            v2f ih = v2(fmaxf(ihd.x, 0.f), fmaxf(ihd.y, 0.f));
            v2f inter = iw * ih;                           // pk
            v2f uni = (qa[q] + ba) - inter;                // pk x2
            v2f cw = 2.0f * hw - iwd;                      // pk fma
            v2f ch = 2.0f * hh - ihd;                      // pk fma
            v2f ca = cw * ch;                              // pk

            float clsa = (q < 4) ? qsel4(c0lo, q) : qsel4(c0hi, q - 4);
            float clsb = (q < 4) ? qsel4(c1lo, q) : qsel4(c1hi, q - 4);

            // cost = 5*l1 + (2*cls+2) - 2*(inter*ca + uni^2)/(uni*ca)
            v2f base = 5.0f * v2(l1x, l1y) + v2(clsa, clsb);   // pk fma
            v2f den  = uni * ca;                               // pk
            v2f r    = v2(__builtin_amdgcn_rcpf(den.x),
                          __builtin_amdgcn_rcpf(den.y));       // ~1 ulp
            v2f num  = uni * uni + inter * ca;                 // pk x2
            v2f res  = -2.0f * (num * r) + base;               // pk x2

            obase[q * npair + pair] = make_float2(res.x, res.y);
        }

        if (!more) break;
        pair = nxt; b0 = nb0; b1 = nb1; L = nL;
    }
}

extern "C" void kernel_launch(void* const* d_in, const int* in_sizes, int n_in,
                              void* d_out, int out_size, void* d_ws, size_t ws_size,
                              hipStream_t stream) {
    const float* logits  = (const float*)d_in[0];  // [16,900,80]
    const float* pboxes  = (const float*)d_in[1];  // [16,900,4]
    const float* tboxes  = (const float*)d_in[2];  // [1600,4]
    const int*   tlabels = (const int*)d_in[3];    // [1600]
    float* out = (float*)d_out;

    const int NQ = in_sizes[1] / 4;   // 14400
    const int T  = in_sizes[2] / 4;   // 1600

    const int nblocks = (NQ + QTILE - 1) / QTILE;  // 1800
    matcher_cost_kernel<<<nblocks, NTHR, 0, stream>>>(logits, pboxes, tboxes,
                                                      tlabels, out, NQ, T);
}